// Round 1
// baseline (620.303 us; speedup 1.0000x reference)
//
#include <hip/hip_runtime.h>

#define BLK 128
constexpr int DIN = 100;
constexpr int H   = 64;
constexpr int G   = 10;
constexpr int NH  = 5;

__global__ __launch_bounds__(BLK) void drnet_kernel(
    const float* __restrict__ dosage, const float* __restrict__ x,
    const float* __restrict__ dW0, const float* __restrict__ db0,
    const float* __restrict__ dW1, const float* __restrict__ db1,
    const float* __restrict__ dbW, const float* __restrict__ dbB,
    const float* __restrict__ W0,  const float* __restrict__ tw0,
    const float* __restrict__ b0,  const float* __restrict__ W1,
    const float* __restrict__ tw1, const float* __restrict__ b1,
    float* __restrict__ outg, float* __restrict__ outq, int Btot)
{
    // transposed per-thread stash: lds[k*BLK + tid]; lanes hit consecutive
    // banks -> conflict-free; each thread uses only its own column -> no barrier
    __shared__ float lds[H * BLK];
    const int tid = threadIdx.x;
    const int i   = blockIdx.x * BLK + tid;
    if (i >= Btot) return;

    const float t = dosage[i];

    // ---------- layer 1: hid = relu(x @ dW0 + db0) ----------
    float acc[H];
    #pragma unroll
    for (int o = 0; o < H; ++o) acc[o] = db0[o];

    const float4* xr = (const float4*)(x + (size_t)i * DIN);
    #pragma unroll 1
    for (int k4 = 0; k4 < DIN / 4; ++k4) {
        const float4 xv = xr[k4];
        const float* w = dW0 + (k4 * 4) * H;   // wave-uniform -> s_load
        #pragma unroll
        for (int o = 0; o < H; ++o) {
            float a = acc[o];
            a = fmaf(xv.x, w[o],         a);
            a = fmaf(xv.y, w[H + o],     a);
            a = fmaf(xv.z, w[2 * H + o], a);
            a = fmaf(xv.w, w[3 * H + o], a);
            acc[o] = a;
        }
    }
    #pragma unroll
    for (int o = 0; o < H; ++o) lds[o * BLK + tid] = fmaxf(acc[o], 0.0f);

    // ---------- layer 2: hid2 = relu(hid @ dW1 + db1) ----------
    #pragma unroll
    for (int o = 0; o < H; ++o) acc[o] = db1[o];
    #pragma unroll 1
    for (int k = 0; k < H; ++k) {
        const float hk = lds[k * BLK + tid];
        const float* w = dW1 + k * H;          // wave-uniform -> s_load
        #pragma unroll
        for (int o = 0; o < H; ++o) acc[o] = fmaf(hk, w[o], acc[o]);
    }
    #pragma unroll
    for (int o = 0; o < H; ++o) acc[o] = fmaxf(acc[o], 0.0f);
    // stash hid2 for the head matmul (dynamic-k reads)
    #pragma unroll
    for (int o = 0; o < H; ++o) lds[o * BLK + tid] = acc[o];

    // ---------- density block: softmax + grid interpolation ----------
    float l[G + 1];
    #pragma unroll
    for (int j = 0; j <= G; ++j) l[j] = dbB[j];
    #pragma unroll
    for (int k = 0; k < H; ++k) {
        const float hk = acc[k];               // unrolled k -> reg index OK
        #pragma unroll
        for (int j = 0; j <= G; ++j) l[j] = fmaf(hk, dbW[k * (G + 1) + j], l[j]);
    }
    float m = l[0];
    #pragma unroll
    for (int j = 1; j <= G; ++j) m = fmaxf(m, l[j]);
    float s = 0.0f;
    #pragma unroll
    for (int j = 0; j <= G; ++j) { l[j] = __expf(l[j] - m); s += l[j]; }

    const float tB    = t * (float)G;
    const float U     = ceilf(tB);
    const float inter = 1.0f - (U - tB);
    const int   Ui    = (int)U;
    int         Li    = Ui - 1; if (Li < 0) Li = 0;
    float pL = 0.0f, pU = 0.0f;
    #pragma unroll
    for (int j = 0; j <= G; ++j) {
        pL = (j == Li) ? l[j] : pL;
        pU = (j == Ui) ? l[j] : pU;
    }
    outg[i] = (pL + (pU - pL) * inter) / s;

    // ---------- multi-head: only the selected bucket's head ----------
    int bucket = (int)floorf(t * (float)NH);
    bucket = min(max(bucket, 0), NH - 1);
    const float* w0h = W0  + (size_t)bucket * H * H;
    const float* t0h = tw0 + bucket * H;
    const float* b0h = b0  + bucket * H;

    // h0 init: t*tw0 + b0 (per-lane loads, 256B-aligned)
    #pragma unroll
    for (int o4 = 0; o4 < H / 4; ++o4) {
        const float4 tw = ((const float4*)t0h)[o4];
        const float4 bb = ((const float4*)b0h)[o4];
        acc[o4 * 4 + 0] = fmaf(t, tw.x, bb.x);
        acc[o4 * 4 + 1] = fmaf(t, tw.y, bb.y);
        acc[o4 * 4 + 2] = fmaf(t, tw.z, bb.z);
        acc[o4 * 4 + 3] = fmaf(t, tw.w, bb.w);
    }
    #pragma unroll 1
    for (int k = 0; k < H; ++k) {
        const float hk = lds[k * BLK + tid];
        const float4* wr = (const float4*)(w0h + k * H);  // per-lane row loads
        #pragma unroll
        for (int o4 = 0; o4 < H / 4; ++o4) {
            const float4 w = wr[o4];
            acc[o4 * 4 + 0] = fmaf(hk, w.x, acc[o4 * 4 + 0]);
            acc[o4 * 4 + 1] = fmaf(hk, w.y, acc[o4 * 4 + 1]);
            acc[o4 * 4 + 2] = fmaf(hk, w.z, acc[o4 * 4 + 2]);
            acc[o4 * 4 + 3] = fmaf(hk, w.w, acc[o4 * 4 + 3]);
        }
    }
    // q = relu(h0) . W1[bucket] + t*tw1[bucket] + b1[bucket]
    const float* w1h = W1 + bucket * H;
    float q = fmaf(t, tw1[bucket], b1[bucket]);
    float qs = 0.0f;
    #pragma unroll
    for (int o4 = 0; o4 < H / 4; ++o4) {
        const float4 w = ((const float4*)w1h)[o4];
        qs += fmaxf(acc[o4 * 4 + 0], 0.0f) * w.x;
        qs += fmaxf(acc[o4 * 4 + 1], 0.0f) * w.y;
        qs += fmaxf(acc[o4 * 4 + 2], 0.0f) * w.z;
        qs += fmaxf(acc[o4 * 4 + 3], 0.0f) * w.w;
    }
    outq[i] = q + qs;
}

extern "C" void kernel_launch(void* const* d_in, const int* in_sizes, int n_in,
                              void* d_out, int out_size, void* d_ws, size_t ws_size,
                              hipStream_t stream) {
    const float* dosage = (const float*)d_in[0];
    const float* x      = (const float*)d_in[1];
    const float* dW0    = (const float*)d_in[2];
    const float* db0    = (const float*)d_in[3];
    const float* dW1    = (const float*)d_in[4];
    const float* db1    = (const float*)d_in[5];
    const float* dbW    = (const float*)d_in[6];
    const float* dbB    = (const float*)d_in[7];
    const float* W0     = (const float*)d_in[8];
    const float* tw0    = (const float*)d_in[9];
    const float* b0     = (const float*)d_in[10];
    const float* W1     = (const float*)d_in[11];
    const float* tw1    = (const float*)d_in[12];
    const float* b1     = (const float*)d_in[13];

    const int Btot = in_sizes[0];
    float* outg = (float*)d_out;
    float* outq = outg + Btot;

    const int grid = (Btot + BLK - 1) / BLK;
    drnet_kernel<<<grid, BLK, 0, stream>>>(dosage, x, dW0, db0, dW1, db1,
                                           dbW, dbB, W0, tw0, b0, W1, tw1, b1,
                                           outg, outq, Btot);
}

// Round 2
// 227.373 us; speedup vs baseline: 2.7281x; 2.7281x over previous
//
#include <hip/hip_runtime.h>

typedef __attribute__((ext_vector_type(8))) short  short8;
typedef __attribute__((ext_vector_type(4))) float  floatx4;

constexpr int DIN = 100;
constexpr int H   = 64;
constexpr int G   = 10;
constexpr int NH  = 5;
constexpr int MWG = 128;                 // rows per block
constexpr int HPITCH = H + 1;            // 65: LDS pitch, breaks bank strides

// fragment counts in ws: dW0 (K=128 padded) 4c*4g=16; dW1 2c*4g=8; dbW 2c*1g=2; W0 5h*2c*4g=40
constexpr int NF_DW0 = 16, NF_DW1 = 8, NF_DBW = 2, NF_W0 = 40;
constexpr int NF_LDS = NF_DW0 + NF_DW1 + NF_DBW;     // 26 staged to LDS
constexpr int NF_TOT = NF_LDS + NF_W0;               // 66

__device__ __forceinline__ unsigned short f2bf(float f) {
    union { float f; unsigned u; } v{f};
    unsigned r = v.u + 0x7FFF + ((v.u >> 16) & 1);   // RNE
    return (unsigned short)(r >> 16);
}

// ---- pre-kernel: pack all weights as bf16 MFMA B-fragments into ws ----
// B-frag layout (16x16x32): lane holds B[k = (lane>>4)*8 + j][n = lane&15]
__global__ __launch_bounds__(64) void pack_kernel(
    const float* __restrict__ dW0, const float* __restrict__ dW1,
    const float* __restrict__ dbW, const float* __restrict__ W0,
    unsigned short* __restrict__ ws)
{
    const int f = blockIdx.x;            // fragment id 0..65
    const int lane = threadIdx.x;        // 0..63
    const int q = lane >> 4, cl = lane & 15;
    float v[8];
    if (f < NF_DW0) {                    // dW0: K padded 100->128 with zeros
        int c = f >> 2, g = f & 3;
        #pragma unroll
        for (int j = 0; j < 8; ++j) {
            int k = c * 32 + q * 8 + j, n = g * 16 + cl;
            v[j] = (k < DIN) ? dW0[k * H + n] : 0.0f;
        }
    } else if (f < NF_DW0 + NF_DW1) {    // dW1: K=64
        int r = f - NF_DW0; int c = r >> 2, g = r & 3;
        #pragma unroll
        for (int j = 0; j < 8; ++j) {
            int k = c * 32 + q * 8 + j, n = g * 16 + cl;
            v[j] = dW1[k * H + n];
        }
    } else if (f < NF_LDS) {             // dbW: K=64, N=11 padded to 16
        int c = f - (NF_DW0 + NF_DW1);
        #pragma unroll
        for (int j = 0; j < 8; ++j) {
            int k = c * 32 + q * 8 + j, n = cl;
            v[j] = (n <= G) ? dbW[k * (G + 1) + n] : 0.0f;
        }
    } else {                             // W0: 5 heads, K=64
        int r = f - NF_LDS; int h = r >> 3; r &= 7; int c = r >> 2, g = r & 3;
        #pragma unroll
        for (int j = 0; j < 8; ++j) {
            int k = c * 32 + q * 8 + j, n = g * 16 + cl;
            v[j] = W0[(h * H + k) * H + n];
        }
    }
    short8 s;
    #pragma unroll
    for (int j = 0; j < 8; ++j) s[j] = (short)f2bf(v[j]);
    *(short8*)(ws + (size_t)(f * 64 + lane) * 8) = s;
}

// ---- main kernel ----
__global__ __launch_bounds__(256) void drnet_mfma(
    const float* __restrict__ dosage, const float* __restrict__ x,
    const float* __restrict__ db0, const float* __restrict__ db1,
    const float* __restrict__ dbB,
    const float* __restrict__ tw0, const float* __restrict__ b0,
    const float* __restrict__ W1, const float* __restrict__ tw1,
    const float* __restrict__ b1,
    const unsigned short* __restrict__ wsfrag,
    float* __restrict__ outg, float* __restrict__ outq)
{
    __shared__ float  hbuf[MWG * HPITCH];        // 33.3 KB, wave-private row slices
    __shared__ short8 wlds[NF_LDS * 64];         // 26 KB weight fragments
    __shared__ float  tbuf[MWG];

    const int tid  = threadIdx.x;
    const int wave = tid >> 6, lane = tid & 63;
    const int q = lane >> 4, cl = lane & 15;
    const int rowbase = blockIdx.x * MWG;
    const int wrow = wave * 32;                  // wave's 32-row slice

    // stage weight frags + dosage
    {
        const floatx4* src = (const floatx4*)wsfrag;
        floatx4* dst = (floatx4*)wlds;
        #pragma unroll
        for (int i = tid; i < NF_LDS * 64; i += 256) dst[i] = src[i];
    }
    if (tid < MWG) tbuf[tid] = dosage[rowbase + tid];
    __syncthreads();

    // t for my 8 C-layout rows (rows 4q+r per mtile)
    float t8[2][4];
    #pragma unroll
    for (int mt = 0; mt < 2; ++mt)
        #pragma unroll
        for (int r = 0; r < 4; ++r) t8[mt][r] = tbuf[wrow + mt * 16 + 4 * q + r];

    floatx4 acc[2][4];

    // ================= layer 1: h1 = relu(x @ dW0 + db0) =================
    #pragma unroll
    for (int mt = 0; mt < 2; ++mt)
        #pragma unroll
        for (int g = 0; g < 4; ++g) acc[mt][g] = (floatx4)0.0f;

    #pragma unroll
    for (int cch = 0; cch < 4; ++cch) {
        short8 a[2];
        #pragma unroll
        for (int mt = 0; mt < 2; ++mt) {
            const float* xr = x + (size_t)(rowbase + wrow + mt * 16 + cl) * DIN;
            float f[8];
            if (cch < 3) {
                floatx4 u0 = *(const floatx4*)(xr + cch * 32 + q * 8);
                floatx4 u1 = *(const floatx4*)(xr + cch * 32 + q * 8 + 4);
                f[0]=u0.x; f[1]=u0.y; f[2]=u0.z; f[3]=u0.w;
                f[4]=u1.x; f[5]=u1.y; f[6]=u1.z; f[7]=u1.w;
            } else {
                if (q == 0) {                     // k=96..99 valid, rest zero
                    floatx4 u0 = *(const floatx4*)(xr + 96);
                    f[0]=u0.x; f[1]=u0.y; f[2]=u0.z; f[3]=u0.w;
                    f[4]=f[5]=f[6]=f[7]=0.0f;
                } else {
                    #pragma unroll
                    for (int j = 0; j < 8; ++j) f[j] = 0.0f;
                }
            }
            short8 s;
            #pragma unroll
            for (int j = 0; j < 8; ++j) s[j] = (short)f2bf(f[j]);
            a[mt] = s;
        }
        #pragma unroll
        for (int g = 0; g < 4; ++g) {
            short8 bf = wlds[(cch * 4 + g) * 64 + lane];
            #pragma unroll
            for (int mt = 0; mt < 2; ++mt)
                acc[mt][g] = __builtin_amdgcn_mfma_f32_16x16x32_bf16(a[mt], bf, acc[mt][g], 0, 0, 0);
        }
    }
    #pragma unroll
    for (int g = 0; g < 4; ++g) {
        float bias = db0[g * 16 + cl];
        #pragma unroll
        for (int mt = 0; mt < 2; ++mt)
            #pragma unroll
            for (int r = 0; r < 4; ++r)
                hbuf[(wrow + mt * 16 + 4 * q + r) * HPITCH + g * 16 + cl] =
                    fmaxf(acc[mt][g][r] + bias, 0.0f);
    }
    // wave-private rows + in-order DS pipe: no barrier needed

    // ================= layer 2: h2 = relu(h1 @ dW1 + db1) =================
    #pragma unroll
    for (int mt = 0; mt < 2; ++mt)
        #pragma unroll
        for (int g = 0; g < 4; ++g) acc[mt][g] = (floatx4)0.0f;

    #pragma unroll
    for (int cch = 0; cch < 2; ++cch) {
        short8 a[2];
        #pragma unroll
        for (int mt = 0; mt < 2; ++mt) {
            const float* hr = hbuf + (wrow + mt * 16 + cl) * HPITCH + cch * 32 + q * 8;
            short8 s;
            #pragma unroll
            for (int j = 0; j < 8; ++j) s[j] = (short)f2bf(hr[j]);
            a[mt] = s;
        }
        #pragma unroll
        for (int g = 0; g < 4; ++g) {
            short8 bf = wlds[(NF_DW0 + cch * 4 + g) * 64 + lane];
            #pragma unroll
            for (int mt = 0; mt < 2; ++mt)
                acc[mt][g] = __builtin_amdgcn_mfma_f32_16x16x32_bf16(a[mt], bf, acc[mt][g], 0, 0, 0);
        }
    }
    #pragma unroll
    for (int g = 0; g < 4; ++g) {
        float bias = db1[g * 16 + cl];
        #pragma unroll
        for (int mt = 0; mt < 2; ++mt)
            #pragma unroll
            for (int r = 0; r < 4; ++r)
                hbuf[(wrow + mt * 16 + 4 * q + r) * HPITCH + g * 16 + cl] =
                    fmaxf(acc[mt][g][r] + bias, 0.0f);
    }

    // A-fragments of h2, reused by density + all 5 heads
    short8 af[2][2];
    #pragma unroll
    for (int mt = 0; mt < 2; ++mt)
        #pragma unroll
        for (int cch = 0; cch < 2; ++cch) {
            const float* hr = hbuf + (wrow + mt * 16 + cl) * HPITCH + cch * 32 + q * 8;
            short8 s;
            #pragma unroll
            for (int j = 0; j < 8; ++j) s[j] = (short)f2bf(hr[j]);
            af[mt][cch] = s;
        }

    // ================= density: softmax(h2 @ dbW + dbB) + interp =================
    floatx4 accd[2];
    accd[0] = (floatx4)0.0f; accd[1] = (floatx4)0.0f;
    #pragma unroll
    for (int cch = 0; cch < 2; ++cch) {
        short8 bf = wlds[(NF_DW0 + NF_DW1 + cch) * 64 + lane];
        #pragma unroll
        for (int mt = 0; mt < 2; ++mt)
            accd[mt] = __builtin_amdgcn_mfma_f32_16x16x32_bf16(af[mt][cch], bf, accd[mt], 0, 0, 0);
    }
    const float dbBv = (cl <= G) ? dbB[cl] : 0.0f;
    float gout[2][4];
    #pragma unroll
    for (int mt = 0; mt < 2; ++mt)
        #pragma unroll
        for (int r = 0; r < 4; ++r) {
            float l = (cl <= G) ? (accd[mt][r] + dbBv) : -1e30f;
            float m = l;
            m = fmaxf(m, __shfl_xor(m, 1)); m = fmaxf(m, __shfl_xor(m, 2));
            m = fmaxf(m, __shfl_xor(m, 4)); m = fmaxf(m, __shfl_xor(m, 8));
            float e = __expf(l - m);
            float s = e;
            s += __shfl_xor(s, 1); s += __shfl_xor(s, 2);
            s += __shfl_xor(s, 4); s += __shfl_xor(s, 8);
            const float t  = t8[mt][r];
            const float tB = t * (float)G;
            const float U  = ceilf(tB);
            const float inter = 1.0f - (U - tB);
            int Ui = (int)U; int Li = Ui - 1; if (Li < 0) Li = 0;
            float pL = __shfl(e, q * 16 + Li);
            float pU = __shfl(e, q * 16 + Ui);
            gout[mt][r] = (pL + (pU - pL) * inter) / s;
        }
    if (cl == 0) {
        #pragma unroll
        for (int mt = 0; mt < 2; ++mt) {
            floatx4 gv = { gout[mt][0], gout[mt][1], gout[mt][2], gout[mt][3] };
            *(floatx4*)(outg + rowbase + wrow + mt * 16 + 4 * q) = gv;
        }
    }

    // ================= heads: all 5 via MFMA, select per row =================
    float qacc[2][4] = {{0,0,0,0},{0,0,0,0}};   // per-lane partials of selected head
    int   bk8[2][4];
    #pragma unroll
    for (int mt = 0; mt < 2; ++mt)
        #pragma unroll
        for (int r = 0; r < 4; ++r) {
            int bk = (int)floorf(t8[mt][r] * (float)NH);
            bk8[mt][r] = min(max(bk, 0), NH - 1);
        }

    #pragma unroll 1
    for (int h = 0; h < NH; ++h) {
        floatx4 acch[2][4];
        #pragma unroll
        for (int mt = 0; mt < 2; ++mt)
            #pragma unroll
            for (int g = 0; g < 4; ++g) acch[mt][g] = (floatx4)0.0f;
        #pragma unroll
        for (int cch = 0; cch < 2; ++cch) {
            #pragma unroll
            for (int g = 0; g < 4; ++g) {
                short8 bf = *(const short8*)(wsfrag +
                    (size_t)((NF_LDS + h * 8 + cch * 4 + g) * 64 + lane) * 8);
                #pragma unroll
                for (int mt = 0; mt < 2; ++mt)
                    acch[mt][g] = __builtin_amdgcn_mfma_f32_16x16x32_bf16(af[mt][cch], bf, acch[mt][g], 0, 0, 0);
            }
        }
        #pragma unroll
        for (int g = 0; g < 4; ++g) {
            const float tw0v = tw0[h * H + g * 16 + cl];
            const float b0v  = b0 [h * H + g * 16 + cl];
            const float w1v  = W1 [h * H + g * 16 + cl];
            #pragma unroll
            for (int mt = 0; mt < 2; ++mt)
                #pragma unroll
                for (int r = 0; r < 4; ++r) {
                    float h0 = acch[mt][g][r] + t8[mt][r] * tw0v + b0v;
                    float c  = fmaxf(h0, 0.0f) * w1v;
                    qacc[mt][r] += (bk8[mt][r] == h) ? c : 0.0f;
                }
        }
    }
    // one butterfly reduce over the 16-lane quad (sums cols 0..63 via 4 g's/lane)
    float qv[2][4];
    #pragma unroll
    for (int mt = 0; mt < 2; ++mt)
        #pragma unroll
        for (int r = 0; r < 4; ++r) {
            float s = qacc[mt][r];
            s += __shfl_xor(s, 1); s += __shfl_xor(s, 2);
            s += __shfl_xor(s, 4); s += __shfl_xor(s, 8);
            const int h = bk8[mt][r];
            qv[mt][r] = s + t8[mt][r] * tw1[h] + b1[h];
        }
    if (cl == 0) {
        #pragma unroll
        for (int mt = 0; mt < 2; ++mt) {
            floatx4 Qv = { qv[mt][0], qv[mt][1], qv[mt][2], qv[mt][3] };
            *(floatx4*)(outq + rowbase + wrow + mt * 16 + 4 * q) = Qv;
        }
    }
}

extern "C" void kernel_launch(void* const* d_in, const int* in_sizes, int n_in,
                              void* d_out, int out_size, void* d_ws, size_t ws_size,
                              hipStream_t stream) {
    const float* dosage = (const float*)d_in[0];
    const float* x      = (const float*)d_in[1];
    const float* dW0    = (const float*)d_in[2];
    const float* db0    = (const float*)d_in[3];
    const float* dW1    = (const float*)d_in[4];
    const float* db1    = (const float*)d_in[5];
    const float* dbW    = (const float*)d_in[6];
    const float* dbB    = (const float*)d_in[7];
    const float* W0     = (const float*)d_in[8];
    const float* tw0    = (const float*)d_in[9];
    const float* b0     = (const float*)d_in[10];
    const float* W1     = (const float*)d_in[11];
    const float* tw1    = (const float*)d_in[12];
    const float* b1     = (const float*)d_in[13];

    const int Btot = in_sizes[0];
    float* outg = (float*)d_out;
    float* outq = outg + Btot;
    unsigned short* ws = (unsigned short*)d_ws;

    pack_kernel<<<NF_TOT, 64, 0, stream>>>(dW0, dW1, dbW, W0, ws);
    drnet_mfma<<<Btot / MWG, 256, 0, stream>>>(dosage, x, db0, db1, dbB,
                                               tw0, b0, W1, tw1, b1,
                                               ws, outg, outq);
}